// Round 3
// baseline (716.402 us; speedup 1.0000x reference)
//
#include <hip/hip_runtime.h>
#include <math.h>
#include <stdint.h>

#define H 256

typedef __attribute__((ext_vector_type(4))) float f32x4;
typedef __attribute__((ext_vector_type(8))) short bf16x8;
typedef __attribute__((ext_vector_type(8))) unsigned short u16x8;

__device__ __forceinline__ float b2f(unsigned short h) { return __uint_as_float(((uint32_t)h) << 16); }
__device__ __forceinline__ unsigned short f2bf(float f) {
    uint32_t u = __float_as_uint(f);
    u = (u + 0x7FFF + ((u >> 16) & 1)) >> 16;   // RNE
    return (unsigned short)u;
}

// ---------------- helpers ----------------
__global__ void k_zero(int* __restrict__ p, int nwords) {
    int i = blockIdx.x * blockDim.x + threadIdx.x;
    if (i < nwords) p[i] = 0;
}

__global__ void k_count(const int* __restrict__ ei, int* __restrict__ deg, int E) {
    int e = blockIdx.x * blockDim.x + threadIdx.x;
    if (e < E) atomicAdd(&deg[ei[E + e]], 1);
}

__global__ void k_dinv(const int* __restrict__ deg, float* __restrict__ dinv, int n) {
    int i = blockIdx.x * blockDim.x + threadIdx.x;
    if (i < n) dinv[i] = rsqrtf((float)(deg[i] + 1));
}

// ---------------- exclusive scan ----------------
#define SCAN_B 512
__global__ void k_scan1(const int* __restrict__ deg, int* __restrict__ row_part,
                        int* __restrict__ bsum, int n) {
    __shared__ int sm[SCAN_B];
    int t = threadIdx.x;
    int i = blockIdx.x * SCAN_B + t;
    int v = (i < n) ? deg[i] : 0;
    sm[t] = v;
    __syncthreads();
    for (int off = 1; off < SCAN_B; off <<= 1) {
        int add = (t >= off) ? sm[t - off] : 0;
        __syncthreads();
        sm[t] += add;
        __syncthreads();
    }
    if (i < n) row_part[i] = sm[t] - v;
    if (t == SCAN_B - 1) bsum[blockIdx.x] = sm[t];
}

__global__ void k_scan2(const int* __restrict__ bsum, int* __restrict__ boff, int nb) {
    __shared__ int sm[1024];
    int t = threadIdx.x;
    int v = (t < nb) ? bsum[t] : 0;
    sm[t] = v;
    __syncthreads();
    for (int off = 1; off < 1024; off <<= 1) {
        int add = (t >= off) ? sm[t - off] : 0;
        __syncthreads();
        sm[t] += add;
        __syncthreads();
    }
    if (t < nb) boff[t] = sm[t] - v;
    if (t == 1023) boff[nb] = sm[t];
}

__global__ void k_scan3(int* __restrict__ row_off, const int* __restrict__ row_part,
                        const int* __restrict__ boff, int n, int nb) {
    int i = blockIdx.x * blockDim.x + threadIdx.x;
    if (i < n) row_off[i] = row_part[i] + boff[i >> 9];
    else if (i == n) row_off[n] = boff[nb];
}

__global__ void k_fill(const int* __restrict__ ei, int* __restrict__ cursor,
                       const int* __restrict__ row_off, int* __restrict__ csr, int E) {
    int e = blockIdx.x * blockDim.x + threadIdx.x;
    if (e >= E) return;
    int src = ei[e];
    int dst = ei[E + e];
    int pos = atomicAdd(&cursor[dst], 1);
    csr[row_off[dst] + pos] = src;
}

// ---------------- W2..W5 -> Wt (transposed, bf16), one launch ----------------
__global__ void k_wprep(const float* __restrict__ Wa, const float* __restrict__ Wb,
                        const float* __restrict__ Wc, const float* __restrict__ Wd,
                        unsigned short* __restrict__ Wt) {
    int idx = blockIdx.x * 256 + threadIdx.x;       // 0 .. 4*65536-1
    int l = idx >> 16, rem = idx & 65535;
    int k = rem >> 8, nn = rem & 255;
    const float* W = (l == 0) ? Wa : (l == 1) ? Wb : (l == 2) ? Wc : Wd;
    Wt[(size_t)l * H * H + nn * H + k] = f2bf(W[rem]);   // Wt[n][k] = W[k][n]
}

// ---------------- layer 1: hws1 = dinv * (x @ W1) ----------------
__global__ void k_layer1(const float* __restrict__ x, const float* __restrict__ W1,
                         const float* __restrict__ dinv, unsigned short* __restrict__ out, int n) {
    int node = blockIdx.x;
    if (node >= n) return;
    int c = threadIdx.x;
    float x0 = x[node * 3 + 0], x1 = x[node * 3 + 1], x2 = x[node * 3 + 2];
    float v = x0 * W1[c] + x1 * W1[H + c] + x2 * W1[2 * H + c];
    out[(size_t)node * H + c] = f2bf(v * dinv[node]);
}

// ---------------- fused: gather(hwsIn)+bias+relu -> A tile -> MFMA @ Wt -> hwsOut ----------------
// h_row(i) = relu(dinv[i]*(sum_{s in N(i)} hwsIn[s] + hwsIn[i]) + b)
// hwsOut(i) = dinv[i] * (h_row(i) @ W)
// Block: 64 rows x 256 cols, 256 threads (4 waves).
__global__ __launch_bounds__(256, 2)
void k_fused(const unsigned short* __restrict__ hwsIn,
             const int* __restrict__ row_off, const int* __restrict__ csr,
             const float* __restrict__ dinv, const float* __restrict__ bias,
             const unsigned short* __restrict__ Wt,
             unsigned short* __restrict__ hwsOut, int n) {
    __shared__ char Atile[64 * 512];     // 64 rows x 256 bf16, XOR-swizzled
    const int tid  = threadIdx.x;
    const int lane = tid & 63;
    const int w    = tid >> 6;
    const int row0 = (int)blockIdx.x * 64;

    // ======== gather phase: wave w -> rows [w*16, w*16+16), 2 rows per iter ========
    {
        const int hf = lane >> 5;        // which of the 2 rows
        const int cl = lane & 31;        // 16B chunk (8 bf16 cols at cl*8)
#pragma unroll
        for (int i = 0; i < 8; i++) {
            int lrow = w * 16 + i * 2 + hf;
            int r = row0 + lrow;
            if (r < n) {
                int s = row_off[r], e = row_off[r + 1];
                float a[8];
                u16x8 sv = *(const u16x8*)(hwsIn + (size_t)r * H + cl * 8);
#pragma unroll
                for (int j = 0; j < 8; j++) a[j] = b2f(sv[j]);
                for (int k = s; k < e; k++) {
                    int src = csr[k];
                    u16x8 v = *(const u16x8*)(hwsIn + (size_t)src * H + cl * 8);
#pragma unroll
                    for (int j = 0; j < 8; j++) a[j] += b2f(v[j]);
                }
                float d = dinv[r];
                float4 b0 = ((const float4*)bias)[cl * 2];
                float4 b1 = ((const float4*)bias)[cl * 2 + 1];
                bf16x8 hv;
                hv[0] = (short)f2bf(fmaxf(fmaf(a[0], d, b0.x), 0.f));
                hv[1] = (short)f2bf(fmaxf(fmaf(a[1], d, b0.y), 0.f));
                hv[2] = (short)f2bf(fmaxf(fmaf(a[2], d, b0.z), 0.f));
                hv[3] = (short)f2bf(fmaxf(fmaf(a[3], d, b0.w), 0.f));
                hv[4] = (short)f2bf(fmaxf(fmaf(a[4], d, b1.x), 0.f));
                hv[5] = (short)f2bf(fmaxf(fmaf(a[5], d, b1.y), 0.f));
                hv[6] = (short)f2bf(fmaxf(fmaf(a[6], d, b1.z), 0.f));
                hv[7] = (short)f2bf(fmaxf(fmaf(a[7], d, b1.w), 0.f));
                *(bf16x8*)(Atile + lrow * 512 + ((cl * 16) ^ ((lrow & 7) << 4))) = hv;
            }
        }
    }
    __syncthreads();

    // ======== GEMM phase: wave w -> rows wm..wm+32, cols wn..wn+128 ========
    const int g   = lane >> 4;
    const int r15 = lane & 15;
    const int wm  = (w & 1) * 32;
    const int wn  = (w >> 1) * 128;

    f32x4 acc[2][8] = {};
    bf16x8 bf[2][8];

#pragma unroll
    for (int nn = 0; nn < 8; nn++)
        bf[0][nn] = *(const bf16x8*)(Wt + (size_t)(wn + nn * 16 + r15) * H + g * 8);

#pragma unroll
    for (int t = 0; t < 8; t++) {
        if (t < 7) {
#pragma unroll
            for (int nn = 0; nn < 8; nn++)
                bf[(t + 1) & 1][nn] =
                    *(const bf16x8*)(Wt + (size_t)(wn + nn * 16 + r15) * H + (t + 1) * 32 + g * 8);
        }
        bf16x8 af[2];
#pragma unroll
        for (int m = 0; m < 2; m++) {
            int arow = wm + m * 16 + r15;
            af[m] = *(const bf16x8*)(Atile + arow * 512 + ((t * 64 + g * 16) ^ ((arow & 7) << 4)));
        }
#pragma unroll
        for (int m = 0; m < 2; m++)
#pragma unroll
            for (int nn = 0; nn < 8; nn++)
                acc[m][nn] = __builtin_amdgcn_mfma_f32_16x16x32_bf16(af[m], bf[t & 1][nn], acc[m][nn], 0, 0, 0);
    }

    // epilogue: C/D layout col = lane&15, row = (lane>>4)*4 + j
#pragma unroll
    for (int m = 0; m < 2; m++) {
#pragma unroll
        for (int j = 0; j < 4; j++) {
            int grow = row0 + wm + m * 16 + g * 4 + j;
            if (grow < n) {
                float d = dinv[grow];
#pragma unroll
                for (int nn = 0; nn < 8; nn++)
                    hwsOut[(size_t)grow * H + wn + nn * 16 + r15] = f2bf(acc[m][nn][j] * d);
            }
        }
    }
}

// ---------------- fused final agg + mean-pool ----------------
// h5(i) = relu(dinv[i]*(sum hws[s] + hws[i]) + b); pooled[batch[i]] += h5(i)
__global__ void k_aggpool(const unsigned short* __restrict__ hws,
                          const int* __restrict__ row_off, const int* __restrict__ csr,
                          const float* __restrict__ dinv, const float* __restrict__ bias,
                          const int* __restrict__ batch,
                          float* __restrict__ pooled, float* __restrict__ counts, int n) {
    int nw = gridDim.x * 4;
    int per = (n + nw - 1) / nw;
    int w = threadIdx.x >> 6, lane = threadIdx.x & 63;
    int s = (blockIdx.x * 4 + w) * per;
    int e = min(n, s + per);
    if (s >= e) return;
    float4 bv = ((const float4*)bias)[lane];
    float p0 = 0.f, p1 = 0.f, p2 = 0.f, p3 = 0.f;
    float cnt = 0.f;
    int cur = batch[s];
    for (int i = s; i < e; i++) {
        int gb = batch[i];
        if (gb != cur) {
            atomicAdd(&pooled[cur * H + lane * 4 + 0], p0);
            atomicAdd(&pooled[cur * H + lane * 4 + 1], p1);
            atomicAdd(&pooled[cur * H + lane * 4 + 2], p2);
            atomicAdd(&pooled[cur * H + lane * 4 + 3], p3);
            if (lane == 0) atomicAdd(&counts[cur], cnt);
            p0 = p1 = p2 = p3 = 0.f; cnt = 0.f; cur = gb;
        }
        ushort4 sv = ((const ushort4*)(hws + (size_t)i * H))[lane];
        float a0 = b2f(sv.x), a1 = b2f(sv.y), a2 = b2f(sv.z), a3 = b2f(sv.w);
        int ks = row_off[i], ke = row_off[i + 1];
        for (int k = ks; k < ke; k++) {
            int src = csr[k];
            ushort4 v = ((const ushort4*)(hws + (size_t)src * H))[lane];
            a0 += b2f(v.x); a1 += b2f(v.y); a2 += b2f(v.z); a3 += b2f(v.w);
        }
        float d = dinv[i];
        p0 += fmaxf(fmaf(a0, d, bv.x), 0.f);
        p1 += fmaxf(fmaf(a1, d, bv.y), 0.f);
        p2 += fmaxf(fmaf(a2, d, bv.z), 0.f);
        p3 += fmaxf(fmaf(a3, d, bv.w), 0.f);
        cnt += 1.f;
    }
    atomicAdd(&pooled[cur * H + lane * 4 + 0], p0);
    atomicAdd(&pooled[cur * H + lane * 4 + 1], p1);
    atomicAdd(&pooled[cur * H + lane * 4 + 2], p2);
    atomicAdd(&pooled[cur * H + lane * 4 + 3], p3);
    if (lane == 0) atomicAdd(&counts[cur], cnt);
}

// ---------------- head ----------------
__global__ void k_out(const float* __restrict__ pooled, const float* __restrict__ counts,
                      const float* __restrict__ Wout, const float* __restrict__ bout,
                      float* __restrict__ out, int G) {
    int t = threadIdx.x;
    if (t >= G * 2) return;
    int g = t >> 1, c = t & 1;
    float s = 0.f;
    for (int k = 0; k < H; k++) s = fmaf(pooled[g * H + k], Wout[k * 2 + c], s);
    float cnt = fmaxf(counts[g], 1.0f);
    float logit = s / cnt + bout[c];
    out[g * 2 + c] = 1.f / (1.f + expf(-logit));
}

// ---------------- launch ----------------
extern "C" void kernel_launch(void* const* d_in, const int* in_sizes, int n_in,
                              void* d_out, int out_size, void* d_ws, size_t ws_size,
                              hipStream_t stream) {
    const float* x    = (const float*)d_in[0];
    const int*   ei   = (const int*)d_in[1];
    const int*   batch= (const int*)d_in[2];
    const float* W1   = (const float*)d_in[3];
    const float* b1   = (const float*)d_in[4];
    const float* Ws[4] = {(const float*)d_in[5], (const float*)d_in[7],
                          (const float*)d_in[9], (const float*)d_in[11]};
    const float* bs[4] = {(const float*)d_in[6], (const float*)d_in[8],
                          (const float*)d_in[10], (const float*)d_in[12]};
    const float* Wout = (const float*)d_in[13];
    const float* bout = (const float*)d_in[14];

    const int N = in_sizes[0] / 3;
    const int E = in_sizes[1] / 2;
    const int G = out_size / 2;
    const int padN = ((N + 127) / 128) * 128;

    char* p = (char*)d_ws;
    auto alloc = [&](size_t bytes) { char* r = p; p += (bytes + 255) & ~(size_t)255; return r; };
    int*    deg      = (int*)alloc((size_t)N * 4);
    int*    cursor   = (int*)alloc((size_t)N * 4);
    float*  counts   = (float*)alloc((size_t)G * 4);
    float*  pooled   = (float*)alloc((size_t)G * H * 4);
    size_t zero_words = ((char*)p - (char*)d_ws) / 4;
    float*  dinv     = (float*)alloc((size_t)N * 4);
    int*    row_part = (int*)alloc((size_t)N * 4);
    int*    row_off  = (int*)alloc((size_t)(N + 1) * 4);
    int*    bsum     = (int*)alloc(1024 * 4);
    int*    boff     = (int*)alloc(1025 * 4);
    int*    csr      = (int*)alloc((size_t)E * 4);
    unsigned short* Wt   = (unsigned short*)alloc((size_t)4 * H * H * 2);
    unsigned short* bufA = (unsigned short*)alloc((size_t)padN * H * 2);
    unsigned short* bufB = (unsigned short*)alloc((size_t)padN * H * 2);

    k_zero<<<(int)((zero_words + 255) / 256), 256, 0, stream>>>((int*)d_ws, (int)zero_words);
    k_count<<<(E + 255) / 256, 256, 0, stream>>>(ei, deg, E);
    k_dinv<<<(N + 255) / 256, 256, 0, stream>>>(deg, dinv, N);

    int nb = (N + SCAN_B - 1) / SCAN_B;
    k_scan1<<<nb, SCAN_B, 0, stream>>>(deg, row_part, bsum, N);
    k_scan2<<<1, 1024, 0, stream>>>(bsum, boff, nb);
    k_scan3<<<(N + 1 + 255) / 256, 256, 0, stream>>>(row_off, row_part, boff, N, nb);
    k_fill<<<(E + 255) / 256, 256, 0, stream>>>(ei, cursor, row_off, csr, E);

    k_wprep<<<4 * H * H / 256, 256, 0, stream>>>(Ws[0], Ws[1], Ws[2], Ws[3], Wt);

    // layer 1: hws1 -> bufA
    k_layer1<<<N, 256, 0, stream>>>(x, W1, dinv, bufA, N);

    // layers 2..5 fused: (agg of hws_{l-1}, bias b_{l-1}, relu) @ W_l * dinv
    const int nblk = (N + 63) / 64;
    k_fused<<<nblk, 256, 0, stream>>>(bufA, row_off, csr, dinv, b1,    Wt + 0 * H * H, bufB, N);
    k_fused<<<nblk, 256, 0, stream>>>(bufB, row_off, csr, dinv, bs[0], Wt + 1 * H * H, bufA, N);
    k_fused<<<nblk, 256, 0, stream>>>(bufA, row_off, csr, dinv, bs[1], Wt + 2 * H * H, bufB, N);
    k_fused<<<nblk, 256, 0, stream>>>(bufB, row_off, csr, dinv, bs[2], Wt + 3 * H * H, bufA, N);

    // final agg (bias b5) + mean pool
    k_aggpool<<<2048, 256, 0, stream>>>(bufA, row_off, csr, dinv, bs[3], batch, pooled, counts, N);
    k_out<<<1, 256, 0, stream>>>(pooled, counts, Wout, bout, (float*)d_out, G);
}

// Round 4
// 538.532 us; speedup vs baseline: 1.3303x; 1.3303x over previous
//
#include <hip/hip_runtime.h>
#include <math.h>
#include <stdint.h>

#define H 256

typedef __attribute__((ext_vector_type(4))) float f32x4;
typedef __attribute__((ext_vector_type(8))) short bf16x8;
typedef __attribute__((ext_vector_type(8))) unsigned short u16x8;

__device__ __forceinline__ float b2f(unsigned short h) { return __uint_as_float(((uint32_t)h) << 16); }
__device__ __forceinline__ unsigned short f2bf(float f) {
    uint32_t u = __float_as_uint(f);
    u = (u + 0x7FFF + ((u >> 16) & 1)) >> 16;   // RNE
    return (unsigned short)u;
}

// ---------------- helpers ----------------
__global__ void k_zero(int* __restrict__ p, int nwords) {
    int i = blockIdx.x * blockDim.x + threadIdx.x;
    if (i < nwords) p[i] = 0;
}

__global__ void k_count(const int* __restrict__ ei, int* __restrict__ deg, int E) {
    int e = blockIdx.x * blockDim.x + threadIdx.x;
    if (e < E) atomicAdd(&deg[ei[E + e]], 1);
}

__global__ void k_dinv(const int* __restrict__ deg, float* __restrict__ dinv, int n) {
    int i = blockIdx.x * blockDim.x + threadIdx.x;
    if (i < n) dinv[i] = rsqrtf((float)(deg[i] + 1));
}

// ---------------- exclusive scan ----------------
#define SCAN_B 512
__global__ void k_scan1(const int* __restrict__ deg, int* __restrict__ row_part,
                        int* __restrict__ bsum, int n) {
    __shared__ int sm[SCAN_B];
    int t = threadIdx.x;
    int i = blockIdx.x * SCAN_B + t;
    int v = (i < n) ? deg[i] : 0;
    sm[t] = v;
    __syncthreads();
    for (int off = 1; off < SCAN_B; off <<= 1) {
        int add = (t >= off) ? sm[t - off] : 0;
        __syncthreads();
        sm[t] += add;
        __syncthreads();
    }
    if (i < n) row_part[i] = sm[t] - v;
    if (t == SCAN_B - 1) bsum[blockIdx.x] = sm[t];
}

__global__ void k_scan2(const int* __restrict__ bsum, int* __restrict__ boff, int nb) {
    __shared__ int sm[1024];
    int t = threadIdx.x;
    int v = (t < nb) ? bsum[t] : 0;
    sm[t] = v;
    __syncthreads();
    for (int off = 1; off < 1024; off <<= 1) {
        int add = (t >= off) ? sm[t - off] : 0;
        __syncthreads();
        sm[t] += add;
        __syncthreads();
    }
    if (t < nb) boff[t] = sm[t] - v;
    if (t == 1023) boff[nb] = sm[t];
}

__global__ void k_scan3(int* __restrict__ row_off, const int* __restrict__ row_part,
                        const int* __restrict__ boff, int n, int nb) {
    int i = blockIdx.x * blockDim.x + threadIdx.x;
    if (i < n) row_off[i] = row_part[i] + boff[i >> 9];
    else if (i == n) row_off[n] = boff[nb];
}

__global__ void k_fill(const int* __restrict__ ei, int* __restrict__ cursor,
                       const int* __restrict__ row_off, int* __restrict__ csr, int E) {
    int e = blockIdx.x * blockDim.x + threadIdx.x;
    if (e >= E) return;
    int src = ei[e];
    int dst = ei[E + e];
    int pos = atomicAdd(&cursor[dst], 1);
    csr[row_off[dst] + pos] = src;
}

// ---------------- W2..W5 -> Wt (transposed, bf16) ----------------
__global__ void k_wprep(const float* __restrict__ Wa, const float* __restrict__ Wb,
                        const float* __restrict__ Wc, const float* __restrict__ Wd,
                        unsigned short* __restrict__ Wt) {
    int idx = blockIdx.x * 256 + threadIdx.x;       // 0 .. 4*65536-1
    int l = idx >> 16, rem = idx & 65535;
    int k = rem >> 8, nn = rem & 255;
    const float* W = (l == 0) ? Wa : (l == 1) ? Wb : (l == 2) ? Wc : Wd;
    Wt[(size_t)l * H * H + nn * H + k] = f2bf(W[rem]);   // Wt[n][k] = W[k][n]
}

// ---------------- layer 1: hws1 = dinv * (x @ W1) ----------------
__global__ void k_layer1(const float* __restrict__ x, const float* __restrict__ W1,
                         const float* __restrict__ dinv, unsigned short* __restrict__ out, int n) {
    int node = blockIdx.x;
    if (node >= n) return;
    int c = threadIdx.x;
    float x0 = x[node * 3 + 0], x1 = x[node * 3 + 1], x2 = x[node * 3 + 2];
    float v = x0 * W1[c] + x1 * W1[H + c] + x2 * W1[2 * H + c];
    out[(size_t)node * H + c] = f2bf(v * dinv[node]);
}

// ---------------- aggregation: out = bf16(relu(dinv[i]*(sum_in hws[src] + hws[i]) + b)) ----------------
// half-wave (32 lanes x 16B = full 512B row) per node pair; 2 interleaved chains for ILP
__global__ void k_agg(const unsigned short* __restrict__ hws, const int* __restrict__ row_off,
                      const int* __restrict__ csr, const float* __restrict__ dinv,
                      const float* __restrict__ bias, unsigned short* __restrict__ out, int n) {
    int hwid = blockIdx.x * 8 + (threadIdx.x >> 5);
    int cl = threadIdx.x & 31;
    int n0 = hwid * 2;
    if (n0 >= n) return;
    int n1 = n0 + 1;
    bool has1 = (n1 < n);

    float a0[8], a1[8];
    u16x8 sv0 = *(const u16x8*)(hws + (size_t)n0 * H + cl * 8);
#pragma unroll
    for (int j = 0; j < 8; j++) a0[j] = b2f(sv0[j]);
    if (has1) {
        u16x8 sv1 = *(const u16x8*)(hws + (size_t)n1 * H + cl * 8);
#pragma unroll
        for (int j = 0; j < 8; j++) a1[j] = b2f(sv1[j]);
    } else {
#pragma unroll
        for (int j = 0; j < 8; j++) a1[j] = 0.f;
    }

    int k0 = row_off[n0], e0 = row_off[n0 + 1];
    int k1 = 0, e1 = 0;
    if (has1) { k1 = e0; e1 = row_off[n0 + 2]; }    // csr rows are contiguous

    int c = min(e0 - k0, e1 - k1);
    for (int i = 0; i < c; i++) {                   // dual independent chains
        int s0 = csr[k0 + i];
        int s1 = csr[k1 + i];
        u16x8 v0 = *(const u16x8*)(hws + (size_t)s0 * H + cl * 8);
        u16x8 v1 = *(const u16x8*)(hws + (size_t)s1 * H + cl * 8);
#pragma unroll
        for (int j = 0; j < 8; j++) { a0[j] += b2f(v0[j]); a1[j] += b2f(v1[j]); }
    }
    k0 += c; k1 += c;
    for (; k0 < e0; k0++) {
        int s0 = csr[k0];
        u16x8 v0 = *(const u16x8*)(hws + (size_t)s0 * H + cl * 8);
#pragma unroll
        for (int j = 0; j < 8; j++) a0[j] += b2f(v0[j]);
    }
    for (; k1 < e1; k1++) {
        int s1 = csr[k1];
        u16x8 v1 = *(const u16x8*)(hws + (size_t)s1 * H + cl * 8);
#pragma unroll
        for (int j = 0; j < 8; j++) a1[j] += b2f(v1[j]);
    }

    float4 b0 = ((const float4*)bias)[cl * 2];
    float4 b1v = ((const float4*)bias)[cl * 2 + 1];
    float bb[8] = {b0.x, b0.y, b0.z, b0.w, b1v.x, b1v.y, b1v.z, b1v.w};

    float d0 = dinv[n0];
    u16x8 o0;
#pragma unroll
    for (int j = 0; j < 8; j++) o0[j] = f2bf(fmaxf(fmaf(a0[j], d0, bb[j]), 0.f));
    *(u16x8*)(out + (size_t)n0 * H + cl * 8) = o0;
    if (has1) {
        float d1 = dinv[n1];
        u16x8 o1;
#pragma unroll
        for (int j = 0; j < 8; j++) o1[j] = f2bf(fmaxf(fmaf(a1[j], d1, bb[j]), 0.f));
        *(u16x8*)(out + (size_t)n1 * H + cl * 8) = o1;
    }
}

// ---------------- streaming MFMA GEMM: out = bf16((A @ W) * dinv[row]) ----------------
// No LDS, no barriers. One wave = 64 rows x 256 cols. A-frags in regs, B-frags from L2.
__global__ __launch_bounds__(256, 2)
void k_gemm(const unsigned short* __restrict__ A, const unsigned short* __restrict__ Wt,
            const float* __restrict__ dinv, unsigned short* __restrict__ out,
            int n, int nwaves) {
    int wv = blockIdx.x * 4 + (threadIdx.x >> 6);
    if (wv >= nwaves) return;
    const int lane = threadIdx.x & 63;
    const int g = lane >> 4, r15 = lane & 15;
    const int row0 = wv * 64;

    // A-tile fragments: rows row0..row0+63, all K=256  (128 VGPR)
    bf16x8 af[4][8];
#pragma unroll
    for (int m = 0; m < 4; m++)
#pragma unroll
        for (int t = 0; t < 8; t++)
            af[m][t] = *(const bf16x8*)(A + (size_t)(row0 + m * 16 + r15) * H + t * 32 + g * 8);

    float dv[16];
#pragma unroll
    for (int m = 0; m < 4; m++)
#pragma unroll
        for (int j = 0; j < 4; j++) {
            int grow = row0 + m * 16 + g * 4 + j;
            dv[m * 4 + j] = (grow < n) ? dinv[grow] : 0.f;
        }

#pragma unroll 1
    for (int nn = 0; nn < 16; nn++) {               // 16-col output strips
        bf16x8 bf[8];
#pragma unroll
        for (int t = 0; t < 8; t++)
            bf[t] = *(const bf16x8*)(Wt + (size_t)(nn * 16 + r15) * H + t * 32 + g * 8);
        f32x4 acc[4] = {};
#pragma unroll
        for (int t = 0; t < 8; t++)
#pragma unroll
            for (int m = 0; m < 4; m++)
                acc[m] = __builtin_amdgcn_mfma_f32_16x16x32_bf16(af[m][t], bf[t], acc[m], 0, 0, 0);
#pragma unroll
        for (int m = 0; m < 4; m++)
#pragma unroll
            for (int j = 0; j < 4; j++) {
                int grow = row0 + m * 16 + g * 4 + j;
                if (grow < n)
                    out[(size_t)grow * H + nn * 16 + r15] = f2bf(acc[m][j] * dv[m * 4 + j]);
            }
    }
}

// ---------------- fused final agg + mean-pool ----------------
__global__ void k_aggpool(const unsigned short* __restrict__ hws,
                          const int* __restrict__ row_off, const int* __restrict__ csr,
                          const float* __restrict__ dinv, const float* __restrict__ bias,
                          const int* __restrict__ batch,
                          float* __restrict__ pooled, float* __restrict__ counts, int n) {
    int nw = gridDim.x * 4;
    int per = (n + nw - 1) / nw;
    int w = threadIdx.x >> 6, lane = threadIdx.x & 63;
    int s = (blockIdx.x * 4 + w) * per;
    int e = min(n, s + per);
    if (s >= e) return;
    float4 bv = ((const float4*)bias)[lane];
    float p0 = 0.f, p1 = 0.f, p2 = 0.f, p3 = 0.f;
    float cnt = 0.f;
    int cur = batch[s];
    for (int i = s; i < e; i++) {
        int gb = batch[i];
        if (gb != cur) {
            atomicAdd(&pooled[cur * H + lane * 4 + 0], p0);
            atomicAdd(&pooled[cur * H + lane * 4 + 1], p1);
            atomicAdd(&pooled[cur * H + lane * 4 + 2], p2);
            atomicAdd(&pooled[cur * H + lane * 4 + 3], p3);
            if (lane == 0) atomicAdd(&counts[cur], cnt);
            p0 = p1 = p2 = p3 = 0.f; cnt = 0.f; cur = gb;
        }
        ushort4 sv = ((const ushort4*)(hws + (size_t)i * H))[lane];
        float a0 = b2f(sv.x), a1 = b2f(sv.y), a2 = b2f(sv.z), a3 = b2f(sv.w);
        int ks = row_off[i], ke = row_off[i + 1];
        for (int k = ks; k < ke; k++) {
            int src = csr[k];
            ushort4 v = ((const ushort4*)(hws + (size_t)src * H))[lane];
            a0 += b2f(v.x); a1 += b2f(v.y); a2 += b2f(v.z); a3 += b2f(v.w);
        }
        float d = dinv[i];
        p0 += fmaxf(fmaf(a0, d, bv.x), 0.f);
        p1 += fmaxf(fmaf(a1, d, bv.y), 0.f);
        p2 += fmaxf(fmaf(a2, d, bv.z), 0.f);
        p3 += fmaxf(fmaf(a3, d, bv.w), 0.f);
        cnt += 1.f;
    }
    atomicAdd(&pooled[cur * H + lane * 4 + 0], p0);
    atomicAdd(&pooled[cur * H + lane * 4 + 1], p1);
    atomicAdd(&pooled[cur * H + lane * 4 + 2], p2);
    atomicAdd(&pooled[cur * H + lane * 4 + 3], p3);
    if (lane == 0) atomicAdd(&counts[cur], cnt);
}

// ---------------- head ----------------
__global__ void k_out(const float* __restrict__ pooled, const float* __restrict__ counts,
                      const float* __restrict__ Wout, const float* __restrict__ bout,
                      float* __restrict__ out, int G) {
    int t = threadIdx.x;
    if (t >= G * 2) return;
    int g = t >> 1, c = t & 1;
    float s = 0.f;
    for (int k = 0; k < H; k++) s = fmaf(pooled[g * H + k], Wout[k * 2 + c], s);
    float cnt = fmaxf(counts[g], 1.0f);
    float logit = s / cnt + bout[c];
    out[g * 2 + c] = 1.f / (1.f + expf(-logit));
}

// ---------------- launch ----------------
extern "C" void kernel_launch(void* const* d_in, const int* in_sizes, int n_in,
                              void* d_out, int out_size, void* d_ws, size_t ws_size,
                              hipStream_t stream) {
    const float* x    = (const float*)d_in[0];
    const int*   ei   = (const int*)d_in[1];
    const int*   batch= (const int*)d_in[2];
    const float* W1   = (const float*)d_in[3];
    const float* b1   = (const float*)d_in[4];
    const float* Ws[4] = {(const float*)d_in[5], (const float*)d_in[7],
                          (const float*)d_in[9], (const float*)d_in[11]};
    const float* bs[4] = {(const float*)d_in[6], (const float*)d_in[8],
                          (const float*)d_in[10], (const float*)d_in[12]};
    const float* Wout = (const float*)d_in[13];
    const float* bout = (const float*)d_in[14];

    const int N = in_sizes[0] / 3;
    const int E = in_sizes[1] / 2;
    const int G = out_size / 2;
    const int padN = ((N + 127) / 128) * 128;

    char* p = (char*)d_ws;
    auto alloc = [&](size_t bytes) { char* r = p; p += (bytes + 255) & ~(size_t)255; return r; };
    int*    deg      = (int*)alloc((size_t)N * 4);
    int*    cursor   = (int*)alloc((size_t)N * 4);
    float*  counts   = (float*)alloc((size_t)G * 4);
    float*  pooled   = (float*)alloc((size_t)G * H * 4);
    size_t zero_words = ((char*)p - (char*)d_ws) / 4;
    float*  dinv     = (float*)alloc((size_t)N * 4);
    int*    row_part = (int*)alloc((size_t)N * 4);
    int*    row_off  = (int*)alloc((size_t)(N + 1) * 4);
    int*    bsum     = (int*)alloc(1024 * 4);
    int*    boff     = (int*)alloc(1025 * 4);
    int*    csr      = (int*)alloc((size_t)E * 4);
    unsigned short* Wt   = (unsigned short*)alloc((size_t)4 * H * H * 2);
    unsigned short* bufA = (unsigned short*)alloc((size_t)padN * H * 2);
    unsigned short* bufB = (unsigned short*)alloc((size_t)padN * H * 2);

    k_zero<<<(int)((zero_words + 255) / 256), 256, 0, stream>>>((int*)d_ws, (int)zero_words);
    k_count<<<(E + 255) / 256, 256, 0, stream>>>(ei, deg, E);
    k_dinv<<<(N + 255) / 256, 256, 0, stream>>>(deg, dinv, N);

    int nb = (N + SCAN_B - 1) / SCAN_B;
    k_scan1<<<nb, SCAN_B, 0, stream>>>(deg, row_part, bsum, N);
    k_scan2<<<1, 1024, 0, stream>>>(bsum, boff, nb);
    k_scan3<<<(N + 1 + 255) / 256, 256, 0, stream>>>(row_off, row_part, boff, N, nb);
    k_fill<<<(E + 255) / 256, 256, 0, stream>>>(ei, cursor, row_off, csr, E);

    k_wprep<<<4 * H * H / 256, 256, 0, stream>>>(Ws[0], Ws[1], Ws[2], Ws[3], Wt);

    // layer 1: hws1 -> bufA
    k_layer1<<<N, 256, 0, stream>>>(x, W1, dinv, bufA, N);

    const int aggblk  = (N + 15) / 16;              // 8 half-waves x 2 nodes per block
    const int nwaves  = (N + 63) / 64;
    const int gemmblk = (nwaves + 3) / 4;

    // layers 2..5: agg (h_l) then streaming GEMM (hws_l)
    const float* biases[4] = {b1, bs[0], bs[1], bs[2]};
    unsigned short* hin  = bufA;
    unsigned short* hout = bufB;
    for (int l = 0; l < 4; l++) {
        k_agg<<<aggblk, 256, 0, stream>>>(hin, row_off, csr, dinv, biases[l], hout, N);
        k_gemm<<<gemmblk, 256, 0, stream>>>(hout, Wt + (size_t)l * H * H, dinv, hin, N, nwaves);
    }

    // final agg (bias b5) + mean pool  (hws5 is in bufA)
    k_aggpool<<<2048, 256, 0, stream>>>(bufA, row_off, csr, dinv, bs[3], batch, pooled, counts, N);
    k_out<<<1, 256, 0, stream>>>(pooled, counts, Wout, bout, (float*)d_out, G);
}